// Round 8
// baseline (906.485 us; speedup 1.0000x reference)
//
#include <hip/hip_runtime.h>
#include <hip/hip_bf16.h>
#include <math.h>

#define NN 50000
#define NFEAT 256
#define NHID 64
#define NCLASS 40
#define EDGES 800000

// coarse buckets: 64 nodes per bucket -> 16KB LDS accumulator, 782 spmm blocks
#define BKT_SH 6
#define BKT_W (1 << BKT_SH)                   // 64
#define NBKT ((NN + BKT_W - 1) / BKT_W)       // 782
#define CAP 8                                 // LDS bin capacity in scat1
#define NBLK1 196
#define CHUNK1 ((EDGES + NBLK1 - 1) / NBLK1)  // 4082

// ---------------- GEMM1: xw = x @ W1  (f32 tiled, 64x64 tile, 4x4 microtile) ----
#define BM 64
#define BK 32
__global__ __launch_bounds__(256) void k_gemm1(const float* __restrict__ x,
                                               const float* __restrict__ W1,
                                               float* __restrict__ xw) {
    __shared__ float xs[BK][BM + 4];
    __shared__ float ws[BK][NHID];
    const int tid = threadIdx.x;
    const int tx  = tid & 15;
    const int ty  = tid >> 4;
    const int r0  = blockIdx.x * BM;

    float acc[4][4] = {};

    for (int kc = 0; kc < NFEAT; kc += BK) {
        #pragma unroll
        for (int p = 0; p < 2; ++p) {
            int e   = tid * 4 + p * 1024;
            int row = e >> 5;
            int k   = e & 31;
            int gr  = r0 + row;
            float4 v = make_float4(0.f, 0.f, 0.f, 0.f);
            if (gr < NN) v = *(const float4*)&x[(size_t)gr * NFEAT + kc + k];
            xs[k + 0][row] = v.x; xs[k + 1][row] = v.y;
            xs[k + 2][row] = v.z; xs[k + 3][row] = v.w;
        }
        #pragma unroll
        for (int p = 0; p < 2; ++p) {
            int e  = tid * 4 + p * 1024;
            int kk = e >> 6;
            int c  = e & 63;
            *(float4*)&ws[kk][c] = *(const float4*)&W1[(size_t)(kc + kk) * NHID + c];
        }
        __syncthreads();
        #pragma unroll
        for (int kk = 0; kk < BK; ++kk) {
            float4 a = *(const float4*)&xs[kk][ty * 4];
            float4 b = *(const float4*)&ws[kk][tx * 4];
            acc[0][0] += a.x * b.x; acc[0][1] += a.x * b.y; acc[0][2] += a.x * b.z; acc[0][3] += a.x * b.w;
            acc[1][0] += a.y * b.x; acc[1][1] += a.y * b.y; acc[1][2] += a.y * b.z; acc[1][3] += a.y * b.w;
            acc[2][0] += a.z * b.x; acc[2][1] += a.z * b.y; acc[2][2] += a.z * b.z; acc[2][3] += a.z * b.w;
            acc[3][0] += a.w * b.x; acc[3][1] += a.w * b.y; acc[3][2] += a.w * b.z; acc[3][3] += a.w * b.w;
        }
        __syncthreads();
    }
    #pragma unroll
    for (int i = 0; i < 4; ++i) {
        int gr = r0 + ty * 4 + i;
        if (gr < NN)
            *(float4*)&xw[(size_t)gr * NHID + tx * 4] =
                make_float4(acc[i][0], acc[i][1], acc[i][2], acc[i][3]);
    }
}

// ---------------- bucket histogram / scan / bin ----------------------------
__global__ __launch_bounds__(1024) void k_zero0(int* __restrict__ bcnt) {
    if (threadIdx.x < NBKT) bcnt[threadIdx.x] = 0;
}

// per-block LDS hist of coarse buckets, one global add per bucket per block
__global__ __launch_bounds__(256) void k_bhist(const int* __restrict__ dst,
                                               int* __restrict__ bcnt) {
    __shared__ int lh[NBKT];
    const int tid = threadIdx.x;
    for (int b = tid; b < NBKT; b += 256) lh[b] = 0;
    __syncthreads();
    int t = blockIdx.x * 256 + tid;
    if (t < EDGES / 4) {
        int4 d = ((const int4*)dst)[t];
        atomicAdd(&lh[d.x >> BKT_SH], 1);
        atomicAdd(&lh[d.y >> BKT_SH], 1);
        atomicAdd(&lh[d.z >> BKT_SH], 1);
        atomicAdd(&lh[d.w >> BKT_SH], 1);
    }
    __syncthreads();
    for (int b = tid; b < NBKT; b += 256) {
        int n = lh[b];
        if (n) atomicAdd(&bcnt[b], n);
    }
}

// single-block exclusive scan of 782 bucket counts
__global__ __launch_bounds__(1024) void k_bscan(const int* __restrict__ bcnt,
                                                int* __restrict__ bbase,
                                                int* __restrict__ bcur) {
    __shared__ int s[1024];
    const int tid = threadIdx.x;
    int v = (tid < NBKT) ? bcnt[tid] : 0;
    s[tid] = v;
    __syncthreads();
    for (int off = 1; off < 1024; off <<= 1) {
        int t = (tid >= off) ? s[tid - off] : 0;
        __syncthreads();
        s[tid] += t;
        __syncthreads();
    }
    if (tid < NBKT) {
        int excl = s[tid] - v;
        bbase[tid] = excl;
        bcur[tid]  = excl;
    }
    if (tid == NBKT - 1) bbase[NBKT] = s[tid];
}

// bin edges into bucket-major staging: LDS bins + bulk reservation + coalesced flush
__global__ __launch_bounds__(256) void k_scat1(const int* __restrict__ src,
                                               const int* __restrict__ dst,
                                               const float* __restrict__ val,
                                               int* __restrict__ bcur,
                                               int2* __restrict__ staging) {
    __shared__ int2 bins[NBKT][CAP];      // 782*8*8 = 50.0 KB
    __shared__ int bincnt[NBKT];
    __shared__ int binbase[NBKT];
    const int tid = threadIdx.x;
    for (int b = tid; b < NBKT; b += 256) bincnt[b] = 0;
    __syncthreads();

    const int base = blockIdx.x * CHUNK1;
    const int end  = min(base + CHUNK1, EDGES);
    for (int e = base + tid; e < end; e += 256) {
        int d = dst[e];
        int b = d >> BKT_SH;
        int2 cv = make_int2(src[e] | ((d & (BKT_W - 1)) << 17), __float_as_int(val[e]));
        int slot = atomicAdd(&bincnt[b], 1);
        if (slot < CAP) {
            bins[b][slot] = cv;
        } else {                          // ~2% tail: direct append
            int p = atomicAdd(&bcur[b], 1);
            staging[p] = cv;
        }
    }
    __syncthreads();

    if (tid < NBKT) {                     // bulk reservations (196 lanes... 782 here)
    }
    for (int b = tid; b < NBKT; b += 256) {
        int n = min(bincnt[b], CAP);
        bincnt[b]  = n;
        binbase[b] = atomicAdd(&bcur[b], n);
    }
    __syncthreads();

    const int wid = tid >> 6, lane = tid & 63;
    for (int b = wid; b < NBKT; b += 4) { // coalesced flush
        int n = bincnt[b], bb = binbase[b];
        for (int i = lane; i < n; i += 64)
            staging[bb + i] = bins[b][i];
    }
}

// ---------------- SPMM via bucket-local LDS accumulator ---------------------
// One block per 64-node bucket (782 blocks, 8 waves). Per wave: 8 contiguous
// staging records batched into registers (one vmcnt group), 8 coalesced 256B
// gathers, 8 LDS atomic accumulates. TLP ~16 waves/CU + 8-deep MLP.
template <bool RELU>
__global__ __launch_bounds__(512, 4) void k_spmm(const float* __restrict__ in,
                                                 const int* __restrict__ bbase,
                                                 const int2* __restrict__ staging,
                                                 const float* __restrict__ bias,
                                                 float* __restrict__ out) {
    __shared__ float accum[BKT_W * NHID];   // 16 KB
    const int tid  = threadIdx.x;
    const int lane = tid & 63;
    const int wv   = tid >> 6;              // 8 waves

    #pragma unroll
    for (int i = tid; i < BKT_W * NHID; i += 512) accum[i] = 0.f;
    __syncthreads();

    const int beg = bbase[blockIdx.x];
    const int end = bbase[blockIdx.x + 1];
    const int n   = end - beg;
    const int nfull = n & ~63;              // chunks of 64 records (8 waves x 8)

    for (int t = 0; t < nfull; t += 64) {
        const int base = beg + t + wv * 8;
        int2 c[8];
        #pragma unroll
        for (int u = 0; u < 8; ++u) c[u] = staging[base + u];
        float g[8];
        #pragma unroll
        for (int u = 0; u < 8; ++u) g[u] = in[(c[u].x & 0x1FFFF) * NHID + lane];
        #pragma unroll
        for (int u = 0; u < 8; ++u)
            atomicAdd(&accum[(c[u].x >> 17) * NHID + lane],
                      __int_as_float(c[u].y) * g[u]);
    }
    for (int i = beg + nfull + wv; i < end; i += 8) {
        int2 c = staging[i];
        float g = in[(c.x & 0x1FFFF) * NHID + lane];
        atomicAdd(&accum[(c.x >> 17) * NHID + lane], __int_as_float(c.y) * g);
    }
    __syncthreads();

    const int nb = blockIdx.x << BKT_SH;
    #pragma unroll
    for (int f4 = tid; f4 < BKT_W * NHID / 4; f4 += 512) {
        int f   = f4 * 4;
        int row = f >> 6;
        int col = f & 63;
        int node = nb + row;
        if (node < NN) {
            float4 a = *(float4*)&accum[f];
            if (RELU) {
                a.x = fmaxf(a.x + bias[col + 0], 0.f);
                a.y = fmaxf(a.y + bias[col + 1], 0.f);
                a.z = fmaxf(a.z + bias[col + 2], 0.f);
                a.w = fmaxf(a.w + bias[col + 3], 0.f);
            }
            *(float4*)&out[(size_t)node * NHID + col] = a;
        }
    }
}

// ---------------- Fused epilogue: heads + reparam + log_softmax -------------
__global__ __launch_bounds__(256) void k_final(const float* __restrict__ g2,
                                               const float* __restrict__ W11,
                                               const float* __restrict__ b11,
                                               const float* __restrict__ W12,
                                               const float* __restrict__ b12,
                                               const float* __restrict__ eps,
                                               float* __restrict__ out) {
    __shared__ float W11l[NHID * NCLASS];
    __shared__ float W12l[NHID * NCLASS];
    __shared__ float bl[2 * NCLASS];
    for (int i = threadIdx.x; i < NHID * NCLASS; i += 256) {
        W11l[i] = W11[i];
        W12l[i] = W12[i];
    }
    if (threadIdx.x < NCLASS) bl[threadIdx.x] = b11[threadIdx.x];
    else if (threadIdx.x < 2 * NCLASS) bl[threadIdx.x] = b12[threadIdx.x - NCLASS];
    __syncthreads();

    const int lane = threadIdx.x & 63;
    const int gw   = (blockIdx.x * 256 + threadIdx.x) >> 6;
    const bool act = lane < NCLASS;
    const int  cc  = act ? lane : NCLASS - 1;

    const int r0 = gw * 4;
    if (r0 >= NN) return;
    const int ur = __builtin_amdgcn_readfirstlane(r0);
    const float* __restrict__ g = g2 + (size_t)ur * NHID;

    float m[4], lg[4];
    #pragma unroll
    for (int i = 0; i < 4; ++i) { m[i] = bl[cc]; lg[i] = bl[NCLASS + cc]; }

    #pragma unroll 4
    for (int k = 0; k < NHID; ++k) {
        float w1 = W11l[k * NCLASS + cc];
        float w2 = W12l[k * NCLASS + cc];
        float ga = g[k], gb = g[NHID + k], gc = g[2 * NHID + k], gd = g[3 * NHID + k];
        m[0] += ga * w1; lg[0] += ga * w2;
        m[1] += gb * w1; lg[1] += gb * w2;
        m[2] += gc * w1; lg[2] += gc * w2;
        m[3] += gd * w1; lg[3] += gd * w2;
    }

    float z[4];
    #pragma unroll
    for (int i = 0; i < 4; ++i)
        z[i] = act ? (eps[(size_t)(ur + i) * NCLASS + lane] * expf(lg[i]) + m[i]) : -1e30f;

    float zmax[4], s[4];
    #pragma unroll
    for (int i = 0; i < 4; ++i) zmax[i] = z[i];
    #pragma unroll
    for (int off = 32; off >= 1; off >>= 1) {
        #pragma unroll
        for (int i = 0; i < 4; ++i) zmax[i] = fmaxf(zmax[i], __shfl_xor(zmax[i], off));
    }
    #pragma unroll
    for (int i = 0; i < 4; ++i) s[i] = act ? expf(z[i] - zmax[i]) : 0.f;
    #pragma unroll
    for (int off = 32; off >= 1; off >>= 1) {
        #pragma unroll
        for (int i = 0; i < 4; ++i) s[i] += __shfl_xor(s[i], off);
    }
    if (act) {
        #pragma unroll
        for (int i = 0; i < 4; ++i)
            out[(size_t)(ur + i) * NCLASS + lane] = z[i] - zmax[i] - logf(s[i]);
    }
}

// ---------------- launcher --------------------------------------------------
extern "C" void kernel_launch(void* const* d_in, const int* in_sizes, int n_in,
                              void* d_out, int out_size, void* d_ws, size_t ws_size,
                              hipStream_t stream) {
    const float* x        = (const float*)d_in[0];
    const int*   edge_src = (const int*)d_in[1];
    const int*   edge_dst = (const int*)d_in[2];
    const float* edge_val = (const float*)d_in[3];
    const float* eps      = (const float*)d_in[4];
    const float* W1       = (const float*)d_in[5];
    const float* b1       = (const float*)d_in[6];
    const float* W11      = (const float*)d_in[7];
    const float* b11      = (const float*)d_in[8];
    const float* W12      = (const float*)d_in[9];
    const float* b12      = (const float*)d_in[10];
    float* out = (float*)d_out;

    // ws layout (staging reused by BOTH spmm passes)
    int2*  staging = (int2*)d_ws;                  // EDGES * 8B
    float* xw      = (float*)(staging + EDGES);    // NN*64
    float* h       = xw + (size_t)NN * NHID;       // NN*64
    int*   bcnt    = (int*)(h + (size_t)NN * NHID);// NBKT
    int*   bbase   = bcnt + NBKT;                  // NBKT+1
    int*   bcur    = bbase + NBKT + 1;             // NBKT
    float* g2 = xw;                                // xw dead after spmmA

    k_gemm1<<<(NN + BM - 1) / BM, 256, 0, stream>>>(x, W1, xw);
    k_zero0<<<1, 1024, 0, stream>>>(bcnt);
    k_bhist<<<(EDGES / 4 + 255) / 256, 256, 0, stream>>>(edge_dst, bcnt);
    k_bscan<<<1, 1024, 0, stream>>>(bcnt, bbase, bcur);
    k_scat1<<<NBLK1, 256, 0, stream>>>(edge_src, edge_dst, edge_val, bcur, staging);
    k_spmm<true><<<NBKT, 512, 0, stream>>>(xw, bbase, staging, b1, h);
    k_spmm<false><<<NBKT, 512, 0, stream>>>(h, bbase, staging, nullptr, g2);
    k_final<<<(NN / 4 + 3) / 4, 256, 0, stream>>>(g2, W11, b11, W12, b12, eps, out);
}

// Round 9
// 305.530 us; speedup vs baseline: 2.9669x; 2.9669x over previous
//
#include <hip/hip_runtime.h>
#include <hip/hip_bf16.h>
#include <math.h>

#define NN 50000
#define NFEAT 256
#define NHID 64
#define NCLASS 40
#define EDGES 800000
#define SCAN_BLK 512

// coarse buckets for the two-pass scatter: 512 nodes per bucket
#define BKT_SH 9
#define BKT_W (1 << BKT_SH)                 // 512
#define NBKT ((NN + BKT_W - 1) / BKT_W)     // 98
#define CAP 64                              // LDS bin capacity (λ≈42)
#define NBLK1 196
#define CHUNK1 ((EDGES + NBLK1 - 1) / NBLK1)  // 4082

// ---------------- GEMM1: xw = x @ W1  (f32 tiled, 128x64 tile, 8x4 microtile) ---
#define BM 128
#define BK 32
__global__ __launch_bounds__(256) void k_gemm1(const float* __restrict__ x,
                                               const float* __restrict__ W1,
                                               float* __restrict__ xw) {
    __shared__ float xs[BK][BM + 4];   // 32 x 132 = 16.9 KB
    __shared__ float ws[BK][NHID];     // 8 KB
    const int tid = threadIdx.x;
    const int tx  = tid & 15;          // col group (4 cols each)
    const int ty  = tid >> 4;          // row group (8 rows each)
    const int r0  = blockIdx.x * BM;

    float acc[8][4] = {};

    for (int kc = 0; kc < NFEAT; kc += BK) {
        // x tile: 128 rows x 32 k = 4096 floats, 4 passes of 256 x float4
        #pragma unroll
        for (int p = 0; p < 4; ++p) {
            int e   = tid * 4 + p * 1024;
            int row = e >> 5;          // 0..127
            int k   = e & 31;
            int gr  = r0 + row;
            float4 v = make_float4(0.f, 0.f, 0.f, 0.f);
            if (gr < NN) v = *(const float4*)&x[(size_t)gr * NFEAT + kc + k];
            xs[k + 0][row] = v.x; xs[k + 1][row] = v.y;
            xs[k + 2][row] = v.z; xs[k + 3][row] = v.w;
        }
        // W tile: 32 k x 64 cols = 2048 floats
        #pragma unroll
        for (int p = 0; p < 2; ++p) {
            int e  = tid * 4 + p * 1024;
            int kk = e >> 6;
            int c  = e & 63;
            *(float4*)&ws[kk][c] = *(const float4*)&W1[(size_t)(kc + kk) * NHID + c];
        }
        __syncthreads();
        #pragma unroll
        for (int kk = 0; kk < BK; ++kk) {
            float4 a0 = *(const float4*)&xs[kk][ty * 8];
            float4 a1 = *(const float4*)&xs[kk][ty * 8 + 4];
            float4 b  = *(const float4*)&ws[kk][tx * 4];
            acc[0][0] += a0.x * b.x; acc[0][1] += a0.x * b.y; acc[0][2] += a0.x * b.z; acc[0][3] += a0.x * b.w;
            acc[1][0] += a0.y * b.x; acc[1][1] += a0.y * b.y; acc[1][2] += a0.y * b.z; acc[1][3] += a0.y * b.w;
            acc[2][0] += a0.z * b.x; acc[2][1] += a0.z * b.y; acc[2][2] += a0.z * b.z; acc[2][3] += a0.z * b.w;
            acc[3][0] += a0.w * b.x; acc[3][1] += a0.w * b.y; acc[3][2] += a0.w * b.z; acc[3][3] += a0.w * b.w;
            acc[4][0] += a1.x * b.x; acc[4][1] += a1.x * b.y; acc[4][2] += a1.x * b.z; acc[4][3] += a1.x * b.w;
            acc[5][0] += a1.y * b.x; acc[5][1] += a1.y * b.y; acc[5][2] += a1.y * b.z; acc[5][3] += a1.y * b.w;
            acc[6][0] += a1.z * b.x; acc[6][1] += a1.z * b.y; acc[6][2] += a1.z * b.z; acc[6][3] += a1.z * b.w;
            acc[7][0] += a1.w * b.x; acc[7][1] += a1.w * b.y; acc[7][2] += a1.w * b.z; acc[7][3] += a1.w * b.w;
        }
        __syncthreads();
    }
    #pragma unroll
    for (int i = 0; i < 8; ++i) {
        int gr = r0 + ty * 8 + i;
        if (gr < NN)
            *(float4*)&xw[(size_t)gr * NHID + tx * 4] =
                make_float4(acc[i][0], acc[i][1], acc[i][2], acc[i][3]);
    }
}

// ---------------- CSR build ------------------------------------------------
__global__ void k_zero(int* __restrict__ count) {
    int i = blockIdx.x * 256 + threadIdx.x;
    if (i < NN) count[i] = 0;
}

__global__ void k_hist(const int* __restrict__ dst, int* __restrict__ count) {
    int t = blockIdx.x * 256 + threadIdx.x;
    if (t < EDGES / 4) {
        int4 d = ((const int4*)dst)[t];
        atomicAdd(&count[d.x], 1);
        atomicAdd(&count[d.y], 1);
        atomicAdd(&count[d.z], 1);
        atomicAdd(&count[d.w], 1);
    }
}

__global__ __launch_bounds__(SCAN_BLK) void k_scanA(const int* __restrict__ count,
                                                    int* __restrict__ tmp,
                                                    int* __restrict__ blocksum) {
    __shared__ int s[SCAN_BLK];
    int i = blockIdx.x * SCAN_BLK + threadIdx.x;
    int v = (i < NN) ? count[i] : 0;
    s[threadIdx.x] = v;
    __syncthreads();
    for (int off = 1; off < SCAN_BLK; off <<= 1) {
        int t = (threadIdx.x >= off) ? s[threadIdx.x - off] : 0;
        __syncthreads();
        s[threadIdx.x] += t;
        __syncthreads();
    }
    if (i < NN) tmp[i] = s[threadIdx.x];
    if (threadIdx.x == SCAN_BLK - 1) blocksum[blockIdx.x] = s[SCAN_BLK - 1];
}

__global__ void k_scanB(const int* __restrict__ blocksum, int* __restrict__ blockoff, int nb) {
    __shared__ int s[128];
    int v = (threadIdx.x < nb) ? blocksum[threadIdx.x] : 0;
    s[threadIdx.x] = v;
    __syncthreads();
    for (int off = 1; off < 128; off <<= 1) {
        int t = (threadIdx.x >= off) ? s[threadIdx.x - off] : 0;
        __syncthreads();
        s[threadIdx.x] += t;
        __syncthreads();
    }
    if (threadIdx.x < nb) blockoff[threadIdx.x] = s[threadIdx.x] - v;  // exclusive
}

// row_ptr + coarse-bucket cursors (bucket start = exclusive prefix at node b*512)
__global__ void k_scanC(const int* __restrict__ tmp, const int* __restrict__ blockoff,
                        const int* __restrict__ count,
                        int* __restrict__ row_ptr, int* __restrict__ bcur) {
    int i = blockIdx.x * 256 + threadIdx.x;
    if (i < NN) {
        int incl = tmp[i] + blockoff[i / SCAN_BLK];
        row_ptr[i + 1] = incl;
        if (i == 0) row_ptr[0] = 0;
        if ((i & (BKT_W - 1)) == 0) bcur[i >> BKT_SH] = incl - count[i];
    }
}

// ---- Pass 1: single read of edges; LDS-bin by coarse bucket; one bulk
// reservation per bin; coalesced flush -> staging writes are ~full lines.
__global__ __launch_bounds__(256) void k_scat1(const int* __restrict__ src,
                                               const int* __restrict__ dst,
                                               const float* __restrict__ val,
                                               int* __restrict__ bcur,
                                               int2* __restrict__ staging) {
    __shared__ int2 bins[NBKT][CAP];      // 98*64*8 = 50 KB
    __shared__ int bincnt[NBKT];
    __shared__ int binbase[NBKT];
    const int tid = threadIdx.x;
    for (int b = tid; b < NBKT; b += 256) bincnt[b] = 0;
    __syncthreads();

    const int base = blockIdx.x * CHUNK1;
    const int end  = min(base + CHUNK1, EDGES);
    for (int e = base + tid; e < end; e += 256) {
        int d = dst[e];
        int b = d >> BKT_SH;
        int2 cv = make_int2(src[e] | ((d & (BKT_W - 1)) << 17), __float_as_int(val[e]));
        int slot = atomicAdd(&bincnt[b], 1);
        if (slot < CAP) {
            bins[b][slot] = cv;
        } else {                          // rare tail: direct append
            int p = atomicAdd(&bcur[b], 1);
            staging[p] = cv;
        }
    }
    __syncthreads();

    if (tid < NBKT) {                     // parallel bulk reservations
        int n = min(bincnt[tid], CAP);
        bincnt[tid]  = n;
        binbase[tid] = atomicAdd(&bcur[tid], n);
    }
    __syncthreads();

    const int wid = tid >> 6, lane = tid & 63;
    for (int b = wid; b < NBKT; b += 4) { // coalesced flush
        int n = bincnt[b], bb = binbase[b];
        for (int i = lane; i < n; i += 64)
            staging[bb + i] = bins[b][i];
    }
}

// ---- Pass 2: one block per coarse bucket; exact placement via LDS cursors;
// writes fully cover the block's own CSR window -> merged writebacks.
__global__ __launch_bounds__(256) void k_scat2(const int* __restrict__ row_ptr,
                                               const int2* __restrict__ staging,
                                               int2* __restrict__ csr) {
    __shared__ int cur[BKT_W];
    const int nb = blockIdx.x << BKT_SH;
    for (int t = threadIdx.x; t < BKT_W; t += 256) {
        int node = nb + t;
        cur[t] = (node < NN) ? row_ptr[node] : 0;
    }
    __syncthreads();
    const int beg = row_ptr[nb];
    const int end = row_ptr[min(nb + BKT_W, NN)];
    for (int i = beg + threadIdx.x; i < end; i += 256) {
        int2 cv = staging[i];
        int dl = cv.x >> 17;
        int p  = atomicAdd(&cur[dl], 1);
        csr[p] = make_int2(cv.x & 0x1FFFF, cv.y);
    }
}

// ---------------- SPMM: out[r,:] = sum_j val_j * in[col_j,:]  (d=64) --------
// One wave per row; 8 gathers in flight, 4 independent acc chains.
template <bool RELU>
__global__ __launch_bounds__(256) void k_spmm(const float* __restrict__ in,
                                              const int* __restrict__ row_ptr,
                                              const int2* __restrict__ csr,
                                              const float* __restrict__ bias,
                                              float* __restrict__ out) {
    const int lane = threadIdx.x & 63;
    int gw = (blockIdx.x * 256 + threadIdx.x) >> 6;
    if (gw >= NN) return;
    const int r   = __builtin_amdgcn_readfirstlane(gw);
    const int beg = row_ptr[r];
    const int end = row_ptr[r + 1];

    float acc0 = 0.f, acc1 = 0.f, acc2 = 0.f, acc3 = 0.f;
    int j = beg;
    for (; j + 7 < end; j += 8) {
        int2 a = csr[j],     b = csr[j + 1], c = csr[j + 2], d = csr[j + 3];
        int2 e = csr[j + 4], f = csr[j + 5], g = csr[j + 6], h = csr[j + 7];
        acc0 += __int_as_float(a.y) * in[(size_t)a.x * NHID + lane];
        acc1 += __int_as_float(b.y) * in[(size_t)b.x * NHID + lane];
        acc2 += __int_as_float(c.y) * in[(size_t)c.x * NHID + lane];
        acc3 += __int_as_float(d.y) * in[(size_t)d.x * NHID + lane];
        acc0 += __int_as_float(e.y) * in[(size_t)e.x * NHID + lane];
        acc1 += __int_as_float(f.y) * in[(size_t)f.x * NHID + lane];
        acc2 += __int_as_float(g.y) * in[(size_t)g.x * NHID + lane];
        acc3 += __int_as_float(h.y) * in[(size_t)h.x * NHID + lane];
    }
    for (; j < end; ++j) {
        int2 a = csr[j];
        acc0 += __int_as_float(a.y) * in[(size_t)a.x * NHID + lane];
    }
    float acc = (acc0 + acc1) + (acc2 + acc3);

    if (RELU)
        out[(size_t)r * NHID + lane] = fmaxf(acc + bias[lane], 0.f);
    else
        out[(size_t)r * NHID + lane] = acc;
}

// ---------------- Fused epilogue: heads + reparam + log_softmax -------------
__global__ __launch_bounds__(256) void k_final(const float* __restrict__ g2,
                                               const float* __restrict__ W11,
                                               const float* __restrict__ b11,
                                               const float* __restrict__ W12,
                                               const float* __restrict__ b12,
                                               const float* __restrict__ eps,
                                               float* __restrict__ out) {
    __shared__ float W11l[NHID * NCLASS];
    __shared__ float W12l[NHID * NCLASS];
    __shared__ float bl[2 * NCLASS];
    for (int i = threadIdx.x; i < NHID * NCLASS; i += 256) {
        W11l[i] = W11[i];
        W12l[i] = W12[i];
    }
    if (threadIdx.x < NCLASS) bl[threadIdx.x] = b11[threadIdx.x];
    else if (threadIdx.x < 2 * NCLASS) bl[threadIdx.x] = b12[threadIdx.x - NCLASS];
    __syncthreads();

    const int lane = threadIdx.x & 63;
    const int gw   = (blockIdx.x * 256 + threadIdx.x) >> 6;
    const bool act = lane < NCLASS;
    const int  cc  = act ? lane : NCLASS - 1;

    const int r0 = gw * 4;
    if (r0 >= NN) return;
    const int ur = __builtin_amdgcn_readfirstlane(r0);
    const float* __restrict__ g = g2 + (size_t)ur * NHID;

    float m[4], lg[4];
    #pragma unroll
    for (int i = 0; i < 4; ++i) { m[i] = bl[cc]; lg[i] = bl[NCLASS + cc]; }

    #pragma unroll 4
    for (int k = 0; k < NHID; ++k) {
        float w1 = W11l[k * NCLASS + cc];
        float w2 = W12l[k * NCLASS + cc];
        float ga = g[k], gb = g[NHID + k], gc = g[2 * NHID + k], gd = g[3 * NHID + k];
        m[0] += ga * w1; lg[0] += ga * w2;
        m[1] += gb * w1; lg[1] += gb * w2;
        m[2] += gc * w1; lg[2] += gc * w2;
        m[3] += gd * w1; lg[3] += gd * w2;
    }

    float z[4];
    #pragma unroll
    for (int i = 0; i < 4; ++i)
        z[i] = act ? (eps[(size_t)(ur + i) * NCLASS + lane] * expf(lg[i]) + m[i]) : -1e30f;

    float zmax[4], s[4];
    #pragma unroll
    for (int i = 0; i < 4; ++i) zmax[i] = z[i];
    #pragma unroll
    for (int off = 32; off >= 1; off >>= 1) {
        #pragma unroll
        for (int i = 0; i < 4; ++i) zmax[i] = fmaxf(zmax[i], __shfl_xor(zmax[i], off));
    }
    #pragma unroll
    for (int i = 0; i < 4; ++i) s[i] = act ? expf(z[i] - zmax[i]) : 0.f;
    #pragma unroll
    for (int off = 32; off >= 1; off >>= 1) {
        #pragma unroll
        for (int i = 0; i < 4; ++i) s[i] += __shfl_xor(s[i], off);
    }
    if (act) {
        #pragma unroll
        for (int i = 0; i < 4; ++i)
            out[(size_t)(ur + i) * NCLASS + lane] = z[i] - zmax[i] - logf(s[i]);
    }
}

// ---------------- launcher --------------------------------------------------
extern "C" void kernel_launch(void* const* d_in, const int* in_sizes, int n_in,
                              void* d_out, int out_size, void* d_ws, size_t ws_size,
                              hipStream_t stream) {
    const float* x        = (const float*)d_in[0];
    const int*   edge_src = (const int*)d_in[1];
    const int*   edge_dst = (const int*)d_in[2];
    const float* edge_val = (const float*)d_in[3];
    const float* eps      = (const float*)d_in[4];
    const float* W1       = (const float*)d_in[5];
    const float* b1       = (const float*)d_in[6];
    const float* W11      = (const float*)d_in[7];
    const float* b11      = (const float*)d_in[8];
    const float* W12      = (const float*)d_in[9];
    const float* b12      = (const float*)d_in[10];
    float* out = (float*)d_out;

    // ws layout; staging aliases h (h first written in spmm1, after scat2)
    int2*  csr     = (int2*)d_ws;                  // EDGES * 8B
    float* xw      = (float*)(csr + EDGES);        // NN*64
    float* h       = xw + (size_t)NN * NHID;       // NN*64
    int2*  staging = (int2*)h;                     // EDGES * 8B (alias)
    int*   count   = (int*)(h + (size_t)NN * NHID);
    int*   tmp     = count + NN;
    int*   row_ptr = tmp + NN;                     // NN+1
    int*   bcur    = row_ptr + (NN + 1);           // NBKT
    int*   blocksum= bcur + NBKT;
    int*   blockoff= blocksum + 128;
    float* g2 = xw;                                // xw dead after spmm1

    const int NB = (NN + SCAN_BLK - 1) / SCAN_BLK; // 98

    k_gemm1<<<(NN + BM - 1) / BM, 256, 0, stream>>>(x, W1, xw);
    k_zero<<<(NN + 255) / 256, 256, 0, stream>>>(count);
    k_hist<<<(EDGES / 4 + 255) / 256, 256, 0, stream>>>(edge_dst, count);
    k_scanA<<<NB, SCAN_BLK, 0, stream>>>(count, tmp, blocksum);
    k_scanB<<<1, 128, 0, stream>>>(blocksum, blockoff, NB);
    k_scanC<<<(NN + 255) / 256, 256, 0, stream>>>(tmp, blockoff, count, row_ptr, bcur);
    k_scat1<<<NBLK1, 256, 0, stream>>>(edge_src, edge_dst, edge_val, bcur, staging);
    k_scat2<<<NBKT, 256, 0, stream>>>(row_ptr, staging, csr);
    k_spmm<true><<<NN / 4, 256, 0, stream>>>(xw, row_ptr, csr, b1, h);
    k_spmm<false><<<NN / 4, 256, 0, stream>>>(h, row_ptr, csr, nullptr, g2);
    k_final<<<(NN / 4 + 3) / 4, 256, 0, stream>>>(g2, W11, b11, W12, b12, eps, out);
}

// Round 10
// 304.306 us; speedup vs baseline: 2.9789x; 1.0040x over previous
//
#include <hip/hip_runtime.h>
#include <hip/hip_bf16.h>
#include <math.h>

#define NN 50000
#define NFEAT 256
#define NHID 64
#define NCLASS 40
#define EDGES 800000
#define SCAN_BLK 512

// coarse buckets for the two-pass scatter: 512 nodes per bucket
#define BKT_SH 9
#define BKT_W (1 << BKT_SH)                 // 512
#define NBKT ((NN + BKT_W - 1) / BKT_W)     // 98
#define CAP 64                              // LDS bin capacity (λ≈42)
#define NBLK1 196
#define CHUNK1 ((EDGES + NBLK1 - 1) / NBLK1)  // 4082

// ---------------- GEMM1: xw = x @ W1  (f32 tiled, 64x64 tile, 4x4 microtile) ----
// BM=64: 782 blocks (~3/CU). BM=128 measured WORSE (391 blocks -> 12% occ, r9).
#define BM 64
#define BK 32
__global__ __launch_bounds__(256) void k_gemm1(const float* __restrict__ x,
                                               const float* __restrict__ W1,
                                               float* __restrict__ xw) {
    __shared__ float xs[BK][BM + 4];
    __shared__ float ws[BK][NHID];
    const int tid = threadIdx.x;
    const int tx  = tid & 15;
    const int ty  = tid >> 4;
    const int r0  = blockIdx.x * BM;

    float acc[4][4] = {};

    for (int kc = 0; kc < NFEAT; kc += BK) {
        #pragma unroll
        for (int p = 0; p < 2; ++p) {
            int e   = tid * 4 + p * 1024;
            int row = e >> 5;
            int k   = e & 31;
            int gr  = r0 + row;
            float4 v = make_float4(0.f, 0.f, 0.f, 0.f);
            if (gr < NN) v = *(const float4*)&x[(size_t)gr * NFEAT + kc + k];
            xs[k + 0][row] = v.x; xs[k + 1][row] = v.y;
            xs[k + 2][row] = v.z; xs[k + 3][row] = v.w;
        }
        #pragma unroll
        for (int p = 0; p < 2; ++p) {
            int e  = tid * 4 + p * 1024;
            int kk = e >> 6;
            int c  = e & 63;
            *(float4*)&ws[kk][c] = *(const float4*)&W1[(size_t)(kc + kk) * NHID + c];
        }
        __syncthreads();
        #pragma unroll
        for (int kk = 0; kk < BK; ++kk) {
            float4 a = *(const float4*)&xs[kk][ty * 4];
            float4 b = *(const float4*)&ws[kk][tx * 4];
            acc[0][0] += a.x * b.x; acc[0][1] += a.x * b.y; acc[0][2] += a.x * b.z; acc[0][3] += a.x * b.w;
            acc[1][0] += a.y * b.x; acc[1][1] += a.y * b.y; acc[1][2] += a.y * b.z; acc[1][3] += a.y * b.w;
            acc[2][0] += a.z * b.x; acc[2][1] += a.z * b.y; acc[2][2] += a.z * b.z; acc[2][3] += a.z * b.w;
            acc[3][0] += a.w * b.x; acc[3][1] += a.w * b.y; acc[3][2] += a.w * b.z; acc[3][3] += a.w * b.w;
        }
        __syncthreads();
    }
    #pragma unroll
    for (int i = 0; i < 4; ++i) {
        int gr = r0 + ty * 4 + i;
        if (gr < NN)
            *(float4*)&xw[(size_t)gr * NHID + tx * 4] =
                make_float4(acc[i][0], acc[i][1], acc[i][2], acc[i][3]);
    }
}

// ---------------- CSR build ------------------------------------------------
__global__ void k_zero(int* __restrict__ count) {
    int i = blockIdx.x * 256 + threadIdx.x;
    if (i < NN) count[i] = 0;
}

__global__ void k_hist(const int* __restrict__ dst, int* __restrict__ count) {
    int t = blockIdx.x * 256 + threadIdx.x;
    if (t < EDGES / 4) {
        int4 d = ((const int4*)dst)[t];
        atomicAdd(&count[d.x], 1);
        atomicAdd(&count[d.y], 1);
        atomicAdd(&count[d.z], 1);
        atomicAdd(&count[d.w], 1);
    }
}

__global__ __launch_bounds__(SCAN_BLK) void k_scanA(const int* __restrict__ count,
                                                    int* __restrict__ tmp,
                                                    int* __restrict__ blocksum) {
    __shared__ int s[SCAN_BLK];
    int i = blockIdx.x * SCAN_BLK + threadIdx.x;
    int v = (i < NN) ? count[i] : 0;
    s[threadIdx.x] = v;
    __syncthreads();
    for (int off = 1; off < SCAN_BLK; off <<= 1) {
        int t = (threadIdx.x >= off) ? s[threadIdx.x - off] : 0;
        __syncthreads();
        s[threadIdx.x] += t;
        __syncthreads();
    }
    if (i < NN) tmp[i] = s[threadIdx.x];
    if (threadIdx.x == SCAN_BLK - 1) blocksum[blockIdx.x] = s[SCAN_BLK - 1];
}

__global__ void k_scanB(const int* __restrict__ blocksum, int* __restrict__ blockoff, int nb) {
    __shared__ int s[128];
    int v = (threadIdx.x < nb) ? blocksum[threadIdx.x] : 0;
    s[threadIdx.x] = v;
    __syncthreads();
    for (int off = 1; off < 128; off <<= 1) {
        int t = (threadIdx.x >= off) ? s[threadIdx.x - off] : 0;
        __syncthreads();
        s[threadIdx.x] += t;
        __syncthreads();
    }
    if (threadIdx.x < nb) blockoff[threadIdx.x] = s[threadIdx.x] - v;  // exclusive
}

// row_ptr + coarse-bucket cursors (bucket start = exclusive prefix at node b*512)
__global__ void k_scanC(const int* __restrict__ tmp, const int* __restrict__ blockoff,
                        const int* __restrict__ count,
                        int* __restrict__ row_ptr, int* __restrict__ bcur) {
    int i = blockIdx.x * 256 + threadIdx.x;
    if (i < NN) {
        int incl = tmp[i] + blockoff[i / SCAN_BLK];
        row_ptr[i + 1] = incl;
        if (i == 0) row_ptr[0] = 0;
        if ((i & (BKT_W - 1)) == 0) bcur[i >> BKT_SH] = incl - count[i];
    }
}

// ---- Pass 1: single read of edges; LDS-bin by coarse bucket; one bulk
// reservation per bin; coalesced flush -> staging writes are ~full lines.
__global__ __launch_bounds__(256) void k_scat1(const int* __restrict__ src,
                                               const int* __restrict__ dst,
                                               const float* __restrict__ val,
                                               int* __restrict__ bcur,
                                               int2* __restrict__ staging) {
    __shared__ int2 bins[NBKT][CAP];      // 98*64*8 = 50 KB
    __shared__ int bincnt[NBKT];
    __shared__ int binbase[NBKT];
    const int tid = threadIdx.x;
    for (int b = tid; b < NBKT; b += 256) bincnt[b] = 0;
    __syncthreads();

    const int base = blockIdx.x * CHUNK1;
    const int end  = min(base + CHUNK1, EDGES);
    for (int e = base + tid; e < end; e += 256) {
        int d = dst[e];
        int b = d >> BKT_SH;
        int2 cv = make_int2(src[e] | ((d & (BKT_W - 1)) << 17), __float_as_int(val[e]));
        int slot = atomicAdd(&bincnt[b], 1);
        if (slot < CAP) {
            bins[b][slot] = cv;
        } else {                          // rare tail: direct append
            int p = atomicAdd(&bcur[b], 1);
            staging[p] = cv;
        }
    }
    __syncthreads();

    if (tid < NBKT) {                     // parallel bulk reservations
        int n = min(bincnt[tid], CAP);
        bincnt[tid]  = n;
        binbase[tid] = atomicAdd(&bcur[tid], n);
    }
    __syncthreads();

    const int wid = tid >> 6, lane = tid & 63;
    for (int b = wid; b < NBKT; b += 4) { // coalesced flush
        int n = bincnt[b], bb = binbase[b];
        for (int i = lane; i < n; i += 64)
            staging[bb + i] = bins[b][i];
    }
}

// ---- Pass 2: one block per coarse bucket; exact placement via LDS cursors;
// writes fully cover the block's own CSR window -> merged writebacks.
__global__ __launch_bounds__(256) void k_scat2(const int* __restrict__ row_ptr,
                                               const int2* __restrict__ staging,
                                               int2* __restrict__ csr) {
    __shared__ int cur[BKT_W];
    const int nb = blockIdx.x << BKT_SH;
    for (int t = threadIdx.x; t < BKT_W; t += 256) {
        int node = nb + t;
        cur[t] = (node < NN) ? row_ptr[node] : 0;
    }
    __syncthreads();
    const int beg = row_ptr[nb];
    const int end = row_ptr[min(nb + BKT_W, NN)];
    for (int i = beg + threadIdx.x; i < end; i += 256) {
        int2 cv = staging[i];
        int dl = cv.x >> 17;
        int p  = atomicAdd(&cur[dl], 1);
        csr[p] = make_int2(cv.x & 0x1FFFF, cv.y);
    }
}

// ---------------- SPMM1: h = relu(spmm(xw) + b1) ----------------------------
__global__ __launch_bounds__(256) void k_spmm1(const float* __restrict__ in,
                                               const int* __restrict__ row_ptr,
                                               const int2* __restrict__ csr,
                                               const float* __restrict__ bias,
                                               float* __restrict__ out) {
    const int lane = threadIdx.x & 63;
    int gw = (blockIdx.x * 256 + threadIdx.x) >> 6;
    if (gw >= NN) return;
    const int r   = __builtin_amdgcn_readfirstlane(gw);
    const int beg = row_ptr[r];
    const int end = row_ptr[r + 1];

    float acc0 = 0.f, acc1 = 0.f, acc2 = 0.f, acc3 = 0.f;
    int j = beg;
    for (; j + 7 < end; j += 8) {
        int2 a = csr[j],     b = csr[j + 1], c = csr[j + 2], d = csr[j + 3];
        int2 e = csr[j + 4], f = csr[j + 5], g = csr[j + 6], h = csr[j + 7];
        acc0 += __int_as_float(a.y) * in[(size_t)a.x * NHID + lane];
        acc1 += __int_as_float(b.y) * in[(size_t)b.x * NHID + lane];
        acc2 += __int_as_float(c.y) * in[(size_t)c.x * NHID + lane];
        acc3 += __int_as_float(d.y) * in[(size_t)d.x * NHID + lane];
        acc0 += __int_as_float(e.y) * in[(size_t)e.x * NHID + lane];
        acc1 += __int_as_float(f.y) * in[(size_t)f.x * NHID + lane];
        acc2 += __int_as_float(g.y) * in[(size_t)g.x * NHID + lane];
        acc3 += __int_as_float(h.y) * in[(size_t)h.x * NHID + lane];
    }
    for (; j < end; ++j) {
        int2 a = csr[j];
        acc0 += __int_as_float(a.y) * in[(size_t)a.x * NHID + lane];
    }
    float acc = (acc0 + acc1) + (acc2 + acc3);
    out[(size_t)r * NHID + lane] = fmaxf(acc + bias[lane], 0.f);
}

// ---------------- Fused SPMM2 + heads + reparam + log_softmax ---------------
// One wave per node row: aggregate g2row = spmm(h) into registers, park in a
// per-wave LDS row, then apply both heads + log_softmax. Deletes g2 round-trip.
__global__ __launch_bounds__(256) void k_spmm_final(const float* __restrict__ h,
                                                    const int* __restrict__ row_ptr,
                                                    const int2* __restrict__ csr,
                                                    const float* __restrict__ W11,
                                                    const float* __restrict__ b11,
                                                    const float* __restrict__ W12,
                                                    const float* __restrict__ b12,
                                                    const float* __restrict__ eps,
                                                    float* __restrict__ out) {
    __shared__ float W11l[NHID * NCLASS];   // 10 KB
    __shared__ float W12l[NHID * NCLASS];   // 10 KB
    __shared__ float bl[2 * NCLASS];
    __shared__ float grow[4][NHID];         // per-wave row buffer, 1 KB
    for (int i = threadIdx.x; i < NHID * NCLASS; i += 256) {
        W11l[i] = W11[i];
        W12l[i] = W12[i];
    }
    if (threadIdx.x < NCLASS) bl[threadIdx.x] = b11[threadIdx.x];
    else if (threadIdx.x < 2 * NCLASS) bl[threadIdx.x] = b12[threadIdx.x - NCLASS];

    const int lane = threadIdx.x & 63;
    const int wv   = threadIdx.x >> 6;
    const int gw   = blockIdx.x * 4 + wv;           // grid = NN/4 exactly
    const int r    = __builtin_amdgcn_readfirstlane(gw);

    // ---- SPMM2: g2row (per-lane element) ----
    const int beg = row_ptr[r];
    const int end = row_ptr[r + 1];
    float acc0 = 0.f, acc1 = 0.f, acc2 = 0.f, acc3 = 0.f;
    int j = beg;
    for (; j + 7 < end; j += 8) {
        int2 a = csr[j],     b = csr[j + 1], c = csr[j + 2], d = csr[j + 3];
        int2 e = csr[j + 4], f = csr[j + 5], g = csr[j + 6], hh = csr[j + 7];
        acc0 += __int_as_float(a.y) * h[(size_t)a.x * NHID + lane];
        acc1 += __int_as_float(b.y) * h[(size_t)b.x * NHID + lane];
        acc2 += __int_as_float(c.y) * h[(size_t)c.x * NHID + lane];
        acc3 += __int_as_float(d.y) * h[(size_t)d.x * NHID + lane];
        acc0 += __int_as_float(e.y) * h[(size_t)e.x * NHID + lane];
        acc1 += __int_as_float(f.y) * h[(size_t)f.x * NHID + lane];
        acc2 += __int_as_float(g.y) * h[(size_t)g.x * NHID + lane];
        acc3 += __int_as_float(hh.y) * h[(size_t)hh.x * NHID + lane];
    }
    for (; j < end; ++j) {
        int2 a = csr[j];
        acc0 += __int_as_float(a.y) * h[(size_t)a.x * NHID + lane];
    }
    grow[wv][lane] = (acc0 + acc1) + (acc2 + acc3);
    __syncthreads();   // also covers the W/b LDS loads above

    // ---- heads: m/lg for this wave's row; lane cc < NCLASS owns a class ----
    const bool act = lane < NCLASS;
    const int  cc  = act ? lane : NCLASS - 1;
    float m  = bl[cc];
    float lg = bl[NCLASS + cc];
    #pragma unroll 8
    for (int k = 0; k < NHID; ++k) {
        float gv = grow[wv][k];             // LDS broadcast
        m  += gv * W11l[k * NCLASS + cc];
        lg += gv * W12l[k * NCLASS + cc];
    }

    float z = act ? (eps[(size_t)r * NCLASS + lane] * expf(lg) + m) : -1e30f;

    float zmax = z;
    #pragma unroll
    for (int off = 32; off >= 1; off >>= 1) zmax = fmaxf(zmax, __shfl_xor(zmax, off));
    float s = act ? expf(z - zmax) : 0.f;
    #pragma unroll
    for (int off = 32; off >= 1; off >>= 1) s += __shfl_xor(s, off);

    if (act) out[(size_t)r * NCLASS + lane] = z - zmax - logf(s);
}

// ---------------- launcher --------------------------------------------------
extern "C" void kernel_launch(void* const* d_in, const int* in_sizes, int n_in,
                              void* d_out, int out_size, void* d_ws, size_t ws_size,
                              hipStream_t stream) {
    const float* x        = (const float*)d_in[0];
    const int*   edge_src = (const int*)d_in[1];
    const int*   edge_dst = (const int*)d_in[2];
    const float* edge_val = (const float*)d_in[3];
    const float* eps      = (const float*)d_in[4];
    const float* W1       = (const float*)d_in[5];
    const float* b1       = (const float*)d_in[6];
    const float* W11      = (const float*)d_in[7];
    const float* b11      = (const float*)d_in[8];
    const float* W12      = (const float*)d_in[9];
    const float* b12      = (const float*)d_in[10];
    float* out = (float*)d_out;

    // ws layout; staging aliases h (h first written in spmm1, after scat2)
    int2*  csr     = (int2*)d_ws;                  // EDGES * 8B
    float* xw      = (float*)(csr + EDGES);        // NN*64
    float* h       = xw + (size_t)NN * NHID;       // NN*64
    int2*  staging = (int2*)h;                     // EDGES * 8B (alias)
    int*   count   = (int*)(h + (size_t)NN * NHID);
    int*   tmp     = count + NN;
    int*   row_ptr = tmp + NN;                     // NN+1
    int*   bcur    = row_ptr + (NN + 1);           // NBKT
    int*   blocksum= bcur + NBKT;
    int*   blockoff= blocksum + 128;

    const int NB = (NN + SCAN_BLK - 1) / SCAN_BLK; // 98

    k_gemm1<<<(NN + BM - 1) / BM, 256, 0, stream>>>(x, W1, xw);
    k_zero<<<(NN + 255) / 256, 256, 0, stream>>>(count);
    k_hist<<<(EDGES / 4 + 255) / 256, 256, 0, stream>>>(edge_dst, count);
    k_scanA<<<NB, SCAN_BLK, 0, stream>>>(count, tmp, blocksum);
    k_scanB<<<1, 128, 0, stream>>>(blocksum, blockoff, NB);
    k_scanC<<<(NN + 255) / 256, 256, 0, stream>>>(tmp, blockoff, count, row_ptr, bcur);
    k_scat1<<<NBLK1, 256, 0, stream>>>(edge_src, edge_dst, edge_val, bcur, staging);
    k_scat2<<<NBKT, 256, 0, stream>>>(row_ptr, staging, csr);
    k_spmm1<<<NN / 4, 256, 0, stream>>>(xw, row_ptr, csr, b1, h);
    k_spmm_final<<<NN / 4, 256, 0, stream>>>(h, row_ptr, csr, W11, b11, W12, b12,
                                             eps, out);
}

// Round 11
// 289.146 us; speedup vs baseline: 3.1350x; 1.0524x over previous
//
#include <hip/hip_runtime.h>
#include <hip/hip_bf16.h>
#include <math.h>

#define NN 50000
#define NFEAT 256
#define NHID 64
#define NCLASS 40
#define EDGES 800000
#define SCAN_BLK 512

// coarse buckets for the two-pass scatter: 512 nodes per bucket
#define BKT_SH 9
#define BKT_W (1 << BKT_SH)                 // 512
#define NBKT ((NN + BKT_W - 1) / BKT_W)     // 98
#define CAP 64                              // LDS bin capacity (λ≈42)
#define NBLK1 196
#define CHUNK1 ((EDGES + NBLK1 - 1) / NBLK1)  // 4082

// ---------------- GEMM1: xw = x @ W1  (f32 tiled, 64x64 tile, 4x4 microtile) ----
// BM=64: 782 blocks (~3/CU). BM=128 measured WORSE (391 blocks -> 12% occ, r9).
#define BM 64
#define BK 32
__global__ __launch_bounds__(256) void k_gemm1(const float* __restrict__ x,
                                               const float* __restrict__ W1,
                                               float* __restrict__ xw) {
    __shared__ float xs[BK][BM + 4];
    __shared__ float ws[BK][NHID];
    const int tid = threadIdx.x;
    const int tx  = tid & 15;
    const int ty  = tid >> 4;
    const int r0  = blockIdx.x * BM;

    float acc[4][4] = {};

    for (int kc = 0; kc < NFEAT; kc += BK) {
        #pragma unroll
        for (int p = 0; p < 2; ++p) {
            int e   = tid * 4 + p * 1024;
            int row = e >> 5;
            int k   = e & 31;
            int gr  = r0 + row;
            float4 v = make_float4(0.f, 0.f, 0.f, 0.f);
            if (gr < NN) v = *(const float4*)&x[(size_t)gr * NFEAT + kc + k];
            xs[k + 0][row] = v.x; xs[k + 1][row] = v.y;
            xs[k + 2][row] = v.z; xs[k + 3][row] = v.w;
        }
        #pragma unroll
        for (int p = 0; p < 2; ++p) {
            int e  = tid * 4 + p * 1024;
            int kk = e >> 6;
            int c  = e & 63;
            *(float4*)&ws[kk][c] = *(const float4*)&W1[(size_t)(kc + kk) * NHID + c];
        }
        __syncthreads();
        #pragma unroll
        for (int kk = 0; kk < BK; ++kk) {
            float4 a = *(const float4*)&xs[kk][ty * 4];
            float4 b = *(const float4*)&ws[kk][tx * 4];
            acc[0][0] += a.x * b.x; acc[0][1] += a.x * b.y; acc[0][2] += a.x * b.z; acc[0][3] += a.x * b.w;
            acc[1][0] += a.y * b.x; acc[1][1] += a.y * b.y; acc[1][2] += a.y * b.z; acc[1][3] += a.y * b.w;
            acc[2][0] += a.z * b.x; acc[2][1] += a.z * b.y; acc[2][2] += a.z * b.z; acc[2][3] += a.z * b.w;
            acc[3][0] += a.w * b.x; acc[3][1] += a.w * b.y; acc[3][2] += a.w * b.z; acc[3][3] += a.w * b.w;
        }
        __syncthreads();
    }
    #pragma unroll
    for (int i = 0; i < 4; ++i) {
        int gr = r0 + ty * 4 + i;
        if (gr < NN)
            *(float4*)&xw[(size_t)gr * NHID + tx * 4] =
                make_float4(acc[i][0], acc[i][1], acc[i][2], acc[i][3]);
    }
}

// ---------------- CSR build ------------------------------------------------
__global__ void k_zero(int* __restrict__ count) {
    int i = blockIdx.x * 256 + threadIdx.x;
    if (i < NN) count[i] = 0;
}

__global__ void k_hist(const int* __restrict__ dst, int* __restrict__ count) {
    int t = blockIdx.x * 256 + threadIdx.x;
    if (t < EDGES / 4) {
        int4 d = ((const int4*)dst)[t];
        atomicAdd(&count[d.x], 1);
        atomicAdd(&count[d.y], 1);
        atomicAdd(&count[d.z], 1);
        atomicAdd(&count[d.w], 1);
    }
}

__global__ __launch_bounds__(SCAN_BLK) void k_scanA(const int* __restrict__ count,
                                                    int* __restrict__ tmp,
                                                    int* __restrict__ blocksum) {
    __shared__ int s[SCAN_BLK];
    int i = blockIdx.x * SCAN_BLK + threadIdx.x;
    int v = (i < NN) ? count[i] : 0;
    s[threadIdx.x] = v;
    __syncthreads();
    for (int off = 1; off < SCAN_BLK; off <<= 1) {
        int t = (threadIdx.x >= off) ? s[threadIdx.x - off] : 0;
        __syncthreads();
        s[threadIdx.x] += t;
        __syncthreads();
    }
    if (i < NN) tmp[i] = s[threadIdx.x];
    if (threadIdx.x == SCAN_BLK - 1) blocksum[blockIdx.x] = s[SCAN_BLK - 1];
}

__global__ void k_scanB(const int* __restrict__ blocksum, int* __restrict__ blockoff, int nb) {
    __shared__ int s[128];
    int v = (threadIdx.x < nb) ? blocksum[threadIdx.x] : 0;
    s[threadIdx.x] = v;
    __syncthreads();
    for (int off = 1; off < 128; off <<= 1) {
        int t = (threadIdx.x >= off) ? s[threadIdx.x - off] : 0;
        __syncthreads();
        s[threadIdx.x] += t;
        __syncthreads();
    }
    if (threadIdx.x < nb) blockoff[threadIdx.x] = s[threadIdx.x] - v;  // exclusive
}

// row_ptr + coarse-bucket cursors (bucket start = exclusive prefix at node b*512)
__global__ void k_scanC(const int* __restrict__ tmp, const int* __restrict__ blockoff,
                        const int* __restrict__ count,
                        int* __restrict__ row_ptr, int* __restrict__ bcur) {
    int i = blockIdx.x * 256 + threadIdx.x;
    if (i < NN) {
        int incl = tmp[i] + blockoff[i / SCAN_BLK];
        row_ptr[i + 1] = incl;
        if (i == 0) row_ptr[0] = 0;
        if ((i & (BKT_W - 1)) == 0) bcur[i >> BKT_SH] = incl - count[i];
    }
}

// ---- Pass 1: single read of edges; LDS-bin by coarse bucket; one bulk
// reservation per bin; coalesced flush -> staging writes are ~full lines.
__global__ __launch_bounds__(256) void k_scat1(const int* __restrict__ src,
                                               const int* __restrict__ dst,
                                               const float* __restrict__ val,
                                               int* __restrict__ bcur,
                                               int2* __restrict__ staging) {
    __shared__ int2 bins[NBKT][CAP];      // 98*64*8 = 50 KB
    __shared__ int bincnt[NBKT];
    __shared__ int binbase[NBKT];
    const int tid = threadIdx.x;
    for (int b = tid; b < NBKT; b += 256) bincnt[b] = 0;
    __syncthreads();

    const int base = blockIdx.x * CHUNK1;
    const int end  = min(base + CHUNK1, EDGES);
    for (int e = base + tid; e < end; e += 256) {
        int d = dst[e];
        int b = d >> BKT_SH;
        int2 cv = make_int2(src[e] | ((d & (BKT_W - 1)) << 17), __float_as_int(val[e]));
        int slot = atomicAdd(&bincnt[b], 1);
        if (slot < CAP) {
            bins[b][slot] = cv;
        } else {                          // rare tail: direct append
            int p = atomicAdd(&bcur[b], 1);
            staging[p] = cv;
        }
    }
    __syncthreads();

    if (tid < NBKT) {                     // parallel bulk reservations
        int n = min(bincnt[tid], CAP);
        bincnt[tid]  = n;
        binbase[tid] = atomicAdd(&bcur[tid], n);
    }
    __syncthreads();

    const int wid = tid >> 6, lane = tid & 63;
    for (int b = wid; b < NBKT; b += 4) { // coalesced flush
        int n = bincnt[b], bb = binbase[b];
        for (int i = lane; i < n; i += 64)
            staging[bb + i] = bins[b][i];
    }
}

// ---- Pass 2: one block per coarse bucket; exact placement via LDS cursors;
// writes fully cover the block's own CSR window -> merged writebacks.
__global__ __launch_bounds__(256) void k_scat2(const int* __restrict__ row_ptr,
                                               const int2* __restrict__ staging,
                                               int2* __restrict__ csr) {
    __shared__ int cur[BKT_W];
    const int nb = blockIdx.x << BKT_SH;
    for (int t = threadIdx.x; t < BKT_W; t += 256) {
        int node = nb + t;
        cur[t] = (node < NN) ? row_ptr[node] : 0;
    }
    __syncthreads();
    const int beg = row_ptr[nb];
    const int end = row_ptr[min(nb + BKT_W, NN)];
    for (int i = beg + threadIdx.x; i < end; i += 256) {
        int2 cv = staging[i];
        int dl = cv.x >> 17;
        int p  = atomicAdd(&cur[dl], 1);
        csr[p] = make_int2(cv.x & 0x1FFFF, cv.y);
    }
}

// ---------------- SPMM1: h = relu(spmm(xw) + b1) ----------------------------
// 2 rows/wave, joint 8+8 interleaved loop: 16 gathers in flight.
__global__ __launch_bounds__(256) void k_spmm1(const float* __restrict__ in,
                                               const int* __restrict__ row_ptr,
                                               const int2* __restrict__ csr,
                                               const float* __restrict__ bias,
                                               float* __restrict__ out) {
    const int lane = threadIdx.x & 63;
    int gw = (blockIdx.x * 256 + threadIdx.x) >> 6;
    const int ra = __builtin_amdgcn_readfirstlane(gw * 2);   // grid exact: ra<NN
    const int rb = ra + 1;
    const int endA = row_ptr[ra + 1];
    const int endB = row_ptr[rb + 1];
    int ja = row_ptr[ra];
    int jb = row_ptr[rb];

    float a0 = 0.f, a1 = 0.f, a2 = 0.f, a3 = 0.f;
    float b0 = 0.f, b1 = 0.f, b2 = 0.f, b3 = 0.f;

    while (ja + 7 < endA && jb + 7 < endB) {
        int2 eA0 = csr[ja],     eA1 = csr[ja + 1], eA2 = csr[ja + 2], eA3 = csr[ja + 3];
        int2 eA4 = csr[ja + 4], eA5 = csr[ja + 5], eA6 = csr[ja + 6], eA7 = csr[ja + 7];
        int2 eB0 = csr[jb],     eB1 = csr[jb + 1], eB2 = csr[jb + 2], eB3 = csr[jb + 3];
        int2 eB4 = csr[jb + 4], eB5 = csr[jb + 5], eB6 = csr[jb + 6], eB7 = csr[jb + 7];
        float gA0 = in[(size_t)eA0.x * NHID + lane], gA1 = in[(size_t)eA1.x * NHID + lane];
        float gA2 = in[(size_t)eA2.x * NHID + lane], gA3 = in[(size_t)eA3.x * NHID + lane];
        float gA4 = in[(size_t)eA4.x * NHID + lane], gA5 = in[(size_t)eA5.x * NHID + lane];
        float gA6 = in[(size_t)eA6.x * NHID + lane], gA7 = in[(size_t)eA7.x * NHID + lane];
        float gB0 = in[(size_t)eB0.x * NHID + lane], gB1 = in[(size_t)eB1.x * NHID + lane];
        float gB2 = in[(size_t)eB2.x * NHID + lane], gB3 = in[(size_t)eB3.x * NHID + lane];
        float gB4 = in[(size_t)eB4.x * NHID + lane], gB5 = in[(size_t)eB5.x * NHID + lane];
        float gB6 = in[(size_t)eB6.x * NHID + lane], gB7 = in[(size_t)eB7.x * NHID + lane];
        a0 += __int_as_float(eA0.y) * gA0; a1 += __int_as_float(eA1.y) * gA1;
        a2 += __int_as_float(eA2.y) * gA2; a3 += __int_as_float(eA3.y) * gA3;
        a0 += __int_as_float(eA4.y) * gA4; a1 += __int_as_float(eA5.y) * gA5;
        a2 += __int_as_float(eA6.y) * gA6; a3 += __int_as_float(eA7.y) * gA7;
        b0 += __int_as_float(eB0.y) * gB0; b1 += __int_as_float(eB1.y) * gB1;
        b2 += __int_as_float(eB2.y) * gB2; b3 += __int_as_float(eB3.y) * gB3;
        b0 += __int_as_float(eB4.y) * gB4; b1 += __int_as_float(eB5.y) * gB5;
        b2 += __int_as_float(eB6.y) * gB6; b3 += __int_as_float(eB7.y) * gB7;
        ja += 8; jb += 8;
    }
    for (; ja + 3 < endA; ja += 4) {
        int2 e0 = csr[ja], e1 = csr[ja + 1], e2 = csr[ja + 2], e3 = csr[ja + 3];
        a0 += __int_as_float(e0.y) * in[(size_t)e0.x * NHID + lane];
        a1 += __int_as_float(e1.y) * in[(size_t)e1.x * NHID + lane];
        a2 += __int_as_float(e2.y) * in[(size_t)e2.x * NHID + lane];
        a3 += __int_as_float(e3.y) * in[(size_t)e3.x * NHID + lane];
    }
    for (; ja < endA; ++ja) {
        int2 e = csr[ja];
        a0 += __int_as_float(e.y) * in[(size_t)e.x * NHID + lane];
    }
    for (; jb + 3 < endB; jb += 4) {
        int2 e0 = csr[jb], e1 = csr[jb + 1], e2 = csr[jb + 2], e3 = csr[jb + 3];
        b0 += __int_as_float(e0.y) * in[(size_t)e0.x * NHID + lane];
        b1 += __int_as_float(e1.y) * in[(size_t)e1.x * NHID + lane];
        b2 += __int_as_float(e2.y) * in[(size_t)e2.x * NHID + lane];
        b3 += __int_as_float(e3.y) * in[(size_t)e3.x * NHID + lane];
    }
    for (; jb < endB; ++jb) {
        int2 e = csr[jb];
        b0 += __int_as_float(e.y) * in[(size_t)e.x * NHID + lane];
    }
    float fb = bias[lane];
    out[(size_t)ra * NHID + lane] = fmaxf(((a0 + a1) + (a2 + a3)) + fb, 0.f);
    out[(size_t)rb * NHID + lane] = fmaxf(((b0 + b1) + (b2 + b3)) + fb, 0.f);
}

// ---------------- Fused SPMM2 + heads + reparam + log_softmax ---------------
// 2 rows/wave (same joint-interleave spmm), W LDS reads shared by both rows.
__global__ __launch_bounds__(256) void k_spmm_final(const float* __restrict__ h,
                                                    const int* __restrict__ row_ptr,
                                                    const int2* __restrict__ csr,
                                                    const float* __restrict__ W11,
                                                    const float* __restrict__ b11,
                                                    const float* __restrict__ W12,
                                                    const float* __restrict__ b12,
                                                    const float* __restrict__ eps,
                                                    float* __restrict__ out) {
    __shared__ float W11l[NHID * NCLASS];   // 10 KB
    __shared__ float W12l[NHID * NCLASS];   // 10 KB
    __shared__ float bl[2 * NCLASS];
    __shared__ float grow[8][NHID];         // 8 rows per block, 2 KB
    for (int i = threadIdx.x; i < NHID * NCLASS; i += 256) {
        W11l[i] = W11[i];
        W12l[i] = W12[i];
    }
    if (threadIdx.x < NCLASS) bl[threadIdx.x] = b11[threadIdx.x];
    else if (threadIdx.x < 2 * NCLASS) bl[threadIdx.x] = b12[threadIdx.x - NCLASS];

    const int lane = threadIdx.x & 63;
    const int wv   = threadIdx.x >> 6;
    const int ra   = __builtin_amdgcn_readfirstlane((blockIdx.x * 4 + wv) * 2);
    const int rb   = ra + 1;

    // ---- SPMM2 for rows ra, rb (joint 8+8 interleave) ----
    const int endA = row_ptr[ra + 1];
    const int endB = row_ptr[rb + 1];
    int ja = row_ptr[ra];
    int jb = row_ptr[rb];
    float a0 = 0.f, a1 = 0.f, a2 = 0.f, a3 = 0.f;
    float b0 = 0.f, b1 = 0.f, b2 = 0.f, b3 = 0.f;

    while (ja + 7 < endA && jb + 7 < endB) {
        int2 eA0 = csr[ja],     eA1 = csr[ja + 1], eA2 = csr[ja + 2], eA3 = csr[ja + 3];
        int2 eA4 = csr[ja + 4], eA5 = csr[ja + 5], eA6 = csr[ja + 6], eA7 = csr[ja + 7];
        int2 eB0 = csr[jb],     eB1 = csr[jb + 1], eB2 = csr[jb + 2], eB3 = csr[jb + 3];
        int2 eB4 = csr[jb + 4], eB5 = csr[jb + 5], eB6 = csr[jb + 6], eB7 = csr[jb + 7];
        float gA0 = h[(size_t)eA0.x * NHID + lane], gA1 = h[(size_t)eA1.x * NHID + lane];
        float gA2 = h[(size_t)eA2.x * NHID + lane], gA3 = h[(size_t)eA3.x * NHID + lane];
        float gA4 = h[(size_t)eA4.x * NHID + lane], gA5 = h[(size_t)eA5.x * NHID + lane];
        float gA6 = h[(size_t)eA6.x * NHID + lane], gA7 = h[(size_t)eA7.x * NHID + lane];
        float gB0 = h[(size_t)eB0.x * NHID + lane], gB1 = h[(size_t)eB1.x * NHID + lane];
        float gB2 = h[(size_t)eB2.x * NHID + lane], gB3 = h[(size_t)eB3.x * NHID + lane];
        float gB4 = h[(size_t)eB4.x * NHID + lane], gB5 = h[(size_t)eB5.x * NHID + lane];
        float gB6 = h[(size_t)eB6.x * NHID + lane], gB7 = h[(size_t)eB7.x * NHID + lane];
        a0 += __int_as_float(eA0.y) * gA0; a1 += __int_as_float(eA1.y) * gA1;
        a2 += __int_as_float(eA2.y) * gA2; a3 += __int_as_float(eA3.y) * gA3;
        a0 += __int_as_float(eA4.y) * gA4; a1 += __int_as_float(eA5.y) * gA5;
        a2 += __int_as_float(eA6.y) * gA6; a3 += __int_as_float(eA7.y) * gA7;
        b0 += __int_as_float(eB0.y) * gB0; b1 += __int_as_float(eB1.y) * gB1;
        b2 += __int_as_float(eB2.y) * gB2; b3 += __int_as_float(eB3.y) * gB3;
        b0 += __int_as_float(eB4.y) * gB4; b1 += __int_as_float(eB5.y) * gB5;
        b2 += __int_as_float(eB6.y) * gB6; b3 += __int_as_float(eB7.y) * gB7;
        ja += 8; jb += 8;
    }
    for (; ja + 3 < endA; ja += 4) {
        int2 e0 = csr[ja], e1 = csr[ja + 1], e2 = csr[ja + 2], e3 = csr[ja + 3];
        a0 += __int_as_float(e0.y) * h[(size_t)e0.x * NHID + lane];
        a1 += __int_as_float(e1.y) * h[(size_t)e1.x * NHID + lane];
        a2 += __int_as_float(e2.y) * h[(size_t)e2.x * NHID + lane];
        a3 += __int_as_float(e3.y) * h[(size_t)e3.x * NHID + lane];
    }
    for (; ja < endA; ++ja) {
        int2 e = csr[ja];
        a0 += __int_as_float(e.y) * h[(size_t)e.x * NHID + lane];
    }
    for (; jb + 3 < endB; jb += 4) {
        int2 e0 = csr[jb], e1 = csr[jb + 1], e2 = csr[jb + 2], e3 = csr[jb + 3];
        b0 += __int_as_float(e0.y) * h[(size_t)e0.x * NHID + lane];
        b1 += __int_as_float(e1.y) * h[(size_t)e1.x * NHID + lane];
        b2 += __int_as_float(e2.y) * h[(size_t)e2.x * NHID + lane];
        b3 += __int_as_float(e3.y) * h[(size_t)e3.x * NHID + lane];
    }
    for (; jb < endB; ++jb) {
        int2 e = csr[jb];
        b0 += __int_as_float(e.y) * h[(size_t)e.x * NHID + lane];
    }
    grow[wv * 2 + 0][lane] = (a0 + a1) + (a2 + a3);
    grow[wv * 2 + 1][lane] = (b0 + b1) + (b2 + b3);
    __syncthreads();   // also covers the W/b LDS loads above

    // ---- heads for both rows; lane cc < NCLASS owns a class ----
    const bool act = lane < NCLASS;
    const int  cc  = act ? lane : NCLASS - 1;
    float m0 = bl[cc],          m1 = m0;
    float l0 = bl[NCLASS + cc], l1 = l0;
    #pragma unroll 8
    for (int k = 0; k < NHID; ++k) {
        float w1 = W11l[k * NCLASS + cc];
        float w2 = W12l[k * NCLASS + cc];
        float g0 = grow[wv * 2 + 0][k];     // LDS broadcast
        float g1 = grow[wv * 2 + 1][k];
        m0 += g0 * w1; l0 += g0 * w2;
        m1 += g1 * w1; l1 += g1 * w2;
    }

    float z0 = act ? (eps[(size_t)ra * NCLASS + lane] * expf(l0) + m0) : -1e30f;
    float z1 = act ? (eps[(size_t)rb * NCLASS + lane] * expf(l1) + m1) : -1e30f;

    float zm0 = z0, zm1 = z1;
    #pragma unroll
    for (int off = 32; off >= 1; off >>= 1) {
        zm0 = fmaxf(zm0, __shfl_xor(zm0, off));
        zm1 = fmaxf(zm1, __shfl_xor(zm1, off));
    }
    float s0 = act ? expf(z0 - zm0) : 0.f;
    float s1 = act ? expf(z1 - zm1) : 0.f;
    #pragma unroll
    for (int off = 32; off >= 1; off >>= 1) {
        s0 += __shfl_xor(s0, off);
        s1 += __shfl_xor(s1, off);
    }
    if (act) {
        out[(size_t)ra * NCLASS + lane] = z0 - zm0 - logf(s0);
        out[(size_t)rb * NCLASS + lane] = z1 - zm1 - logf(s1);
    }
}

// ---------------- launcher --------------------------------------------------
extern "C" void kernel_launch(void* const* d_in, const int* in_sizes, int n_in,
                              void* d_out, int out_size, void* d_ws, size_t ws_size,
                              hipStream_t stream) {
    const float* x        = (const float*)d_in[0];
    const int*   edge_src = (const int*)d_in[1];
    const int*   edge_dst = (const int*)d_in[2];
    const float* edge_val = (const float*)d_in[3];
    const float* eps      = (const float*)d_in[4];
    const float* W1       = (const float*)d_in[5];
    const float* b1       = (const float*)d_in[6];
    const float* W11      = (const float*)d_in[7];
    const float* b11      = (const float*)d_in[8];
    const float* W12      = (const float*)d_in[9];
    const float* b12      = (const float*)d_in[10];
    float* out = (float*)d_out;

    // ws layout; staging aliases h (h first written in spmm1, after scat2)
    int2*  csr     = (int2*)d_ws;                  // EDGES * 8B
    float* xw      = (float*)(csr + EDGES);        // NN*64
    float* h       = xw + (size_t)NN * NHID;       // NN*64
    int2*  staging = (int2*)h;                     // EDGES * 8B (alias)
    int*   count   = (int*)(h + (size_t)NN * NHID);
    int*   tmp     = count + NN;
    int*   row_ptr = tmp + NN;                     // NN+1
    int*   bcur    = row_ptr + (NN + 1);           // NBKT
    int*   blocksum= bcur + NBKT;
    int*   blockoff= blocksum + 128;

    const int NB = (NN + SCAN_BLK - 1) / SCAN_BLK; // 98

    k_gemm1<<<(NN + BM - 1) / BM, 256, 0, stream>>>(x, W1, xw);
    k_zero<<<(NN + 255) / 256, 256, 0, stream>>>(count);
    k_hist<<<(EDGES / 4 + 255) / 256, 256, 0, stream>>>(edge_dst, count);
    k_scanA<<<NB, SCAN_BLK, 0, stream>>>(count, tmp, blocksum);
    k_scanB<<<1, 128, 0, stream>>>(blocksum, blockoff, NB);
    k_scanC<<<(NN + 255) / 256, 256, 0, stream>>>(tmp, blockoff, count, row_ptr, bcur);
    k_scat1<<<NBLK1, 256, 0, stream>>>(edge_src, edge_dst, edge_val, bcur, staging);
    k_scat2<<<NBKT, 256, 0, stream>>>(row_ptr, staging, csr);
    k_spmm1<<<NN / 8, 256, 0, stream>>>(xw, row_ptr, csr, b1, h);
    k_spmm_final<<<NN / 8, 256, 0, stream>>>(h, row_ptr, csr, W11, b11, W12, b12,
                                             eps, out);
}

// Round 12
// 286.531 us; speedup vs baseline: 3.1637x; 1.0091x over previous
//
#include <hip/hip_runtime.h>
#include <hip/hip_bf16.h>
#include <math.h>

#define NN 50000
#define NFEAT 256
#define NHID 64
#define NCLASS 40
#define EDGES 800000
#define SCAN_BLK 512

// coarse buckets for the two-pass scatter: 512 nodes per bucket
#define BKT_SH 9
#define BKT_W (1 << BKT_SH)                 // 512
#define NBKT ((NN + BKT_W - 1) / BKT_W)     // 98
#define CAP 64                              // LDS bin capacity (λ≈42)
#define NBLK1 196
#define CHUNK1 ((EDGES + NBLK1 - 1) / NBLK1)  // 4082

// ---------------- GEMM1: xw = x @ W1  (f32 tiled, 64x64 tile, 4x4 microtile) ----
// BM=64: 782 blocks (~3/CU). BM=128 measured WORSE (391 blocks -> 12% occ, r9).
#define BM 64
#define BK 32
__global__ __launch_bounds__(256) void k_gemm1(const float* __restrict__ x,
                                               const float* __restrict__ W1,
                                               float* __restrict__ xw) {
    __shared__ float xs[BK][BM + 4];
    __shared__ float ws[BK][NHID];
    const int tid = threadIdx.x;
    const int tx  = tid & 15;
    const int ty  = tid >> 4;
    const int r0  = blockIdx.x * BM;

    float acc[4][4] = {};

    for (int kc = 0; kc < NFEAT; kc += BK) {
        #pragma unroll
        for (int p = 0; p < 2; ++p) {
            int e   = tid * 4 + p * 1024;
            int row = e >> 5;
            int k   = e & 31;
            int gr  = r0 + row;
            float4 v = make_float4(0.f, 0.f, 0.f, 0.f);
            if (gr < NN) v = *(const float4*)&x[(size_t)gr * NFEAT + kc + k];
            xs[k + 0][row] = v.x; xs[k + 1][row] = v.y;
            xs[k + 2][row] = v.z; xs[k + 3][row] = v.w;
        }
        #pragma unroll
        for (int p = 0; p < 2; ++p) {
            int e  = tid * 4 + p * 1024;
            int kk = e >> 6;
            int c  = e & 63;
            *(float4*)&ws[kk][c] = *(const float4*)&W1[(size_t)(kc + kk) * NHID + c];
        }
        __syncthreads();
        #pragma unroll
        for (int kk = 0; kk < BK; ++kk) {
            float4 a = *(const float4*)&xs[kk][ty * 4];
            float4 b = *(const float4*)&ws[kk][tx * 4];
            acc[0][0] += a.x * b.x; acc[0][1] += a.x * b.y; acc[0][2] += a.x * b.z; acc[0][3] += a.x * b.w;
            acc[1][0] += a.y * b.x; acc[1][1] += a.y * b.y; acc[1][2] += a.y * b.z; acc[1][3] += a.y * b.w;
            acc[2][0] += a.z * b.x; acc[2][1] += a.z * b.y; acc[2][2] += a.z * b.z; acc[2][3] += a.z * b.w;
            acc[3][0] += a.w * b.x; acc[3][1] += a.w * b.y; acc[3][2] += a.w * b.z; acc[3][3] += a.w * b.w;
        }
        __syncthreads();
    }
    #pragma unroll
    for (int i = 0; i < 4; ++i) {
        int gr = r0 + ty * 4 + i;
        if (gr < NN)
            *(float4*)&xw[(size_t)gr * NHID + tx * 4] =
                make_float4(acc[i][0], acc[i][1], acc[i][2], acc[i][3]);
    }
}

// ---------------- CSR build ------------------------------------------------
__global__ void k_zero(int* __restrict__ count) {
    int i = blockIdx.x * 256 + threadIdx.x;
    if (i < NN) count[i] = 0;
}

__global__ void k_hist(const int* __restrict__ dst, int* __restrict__ count) {
    int t = blockIdx.x * 256 + threadIdx.x;
    if (t < EDGES / 4) {
        int4 d = ((const int4*)dst)[t];
        atomicAdd(&count[d.x], 1);
        atomicAdd(&count[d.y], 1);
        atomicAdd(&count[d.z], 1);
        atomicAdd(&count[d.w], 1);
    }
}

__global__ __launch_bounds__(SCAN_BLK) void k_scanA(const int* __restrict__ count,
                                                    int* __restrict__ tmp,
                                                    int* __restrict__ blocksum) {
    __shared__ int s[SCAN_BLK];
    int i = blockIdx.x * SCAN_BLK + threadIdx.x;
    int v = (i < NN) ? count[i] : 0;
    s[threadIdx.x] = v;
    __syncthreads();
    for (int off = 1; off < SCAN_BLK; off <<= 1) {
        int t = (threadIdx.x >= off) ? s[threadIdx.x - off] : 0;
        __syncthreads();
        s[threadIdx.x] += t;
        __syncthreads();
    }
    if (i < NN) tmp[i] = s[threadIdx.x];
    if (threadIdx.x == SCAN_BLK - 1) blocksum[blockIdx.x] = s[SCAN_BLK - 1];
}

__global__ void k_scanB(const int* __restrict__ blocksum, int* __restrict__ blockoff, int nb) {
    __shared__ int s[128];
    int v = (threadIdx.x < nb) ? blocksum[threadIdx.x] : 0;
    s[threadIdx.x] = v;
    __syncthreads();
    for (int off = 1; off < 128; off <<= 1) {
        int t = (threadIdx.x >= off) ? s[threadIdx.x - off] : 0;
        __syncthreads();
        s[threadIdx.x] += t;
        __syncthreads();
    }
    if (threadIdx.x < nb) blockoff[threadIdx.x] = s[threadIdx.x] - v;  // exclusive
}

// row_ptr + coarse-bucket cursors (bucket start = exclusive prefix at node b*512)
__global__ void k_scanC(const int* __restrict__ tmp, const int* __restrict__ blockoff,
                        const int* __restrict__ count,
                        int* __restrict__ row_ptr, int* __restrict__ bcur) {
    int i = blockIdx.x * 256 + threadIdx.x;
    if (i < NN) {
        int incl = tmp[i] + blockoff[i / SCAN_BLK];
        row_ptr[i + 1] = incl;
        if (i == 0) row_ptr[0] = 0;
        if ((i & (BKT_W - 1)) == 0) bcur[i >> BKT_SH] = incl - count[i];
    }
}

// ---- Pass 1: single read of edges; LDS-bin by coarse bucket; one bulk
// reservation per bin; coalesced flush -> staging writes are ~full lines.
__global__ __launch_bounds__(256) void k_scat1(const int* __restrict__ src,
                                               const int* __restrict__ dst,
                                               const float* __restrict__ val,
                                               int* __restrict__ bcur,
                                               int2* __restrict__ staging) {
    __shared__ int2 bins[NBKT][CAP];      // 98*64*8 = 50 KB
    __shared__ int bincnt[NBKT];
    __shared__ int binbase[NBKT];
    const int tid = threadIdx.x;
    for (int b = tid; b < NBKT; b += 256) bincnt[b] = 0;
    __syncthreads();

    const int base = blockIdx.x * CHUNK1;
    const int end  = min(base + CHUNK1, EDGES);
    for (int e = base + tid; e < end; e += 256) {
        int d = dst[e];
        int b = d >> BKT_SH;
        int2 cv = make_int2(src[e] | ((d & (BKT_W - 1)) << 17), __float_as_int(val[e]));
        int slot = atomicAdd(&bincnt[b], 1);
        if (slot < CAP) {
            bins[b][slot] = cv;
        } else {                          // rare tail: direct append
            int p = atomicAdd(&bcur[b], 1);
            staging[p] = cv;
        }
    }
    __syncthreads();

    if (tid < NBKT) {                     // parallel bulk reservations
        int n = min(bincnt[tid], CAP);
        bincnt[tid]  = n;
        binbase[tid] = atomicAdd(&bcur[tid], n);
    }
    __syncthreads();

    const int wid = tid >> 6, lane = tid & 63;
    for (int b = wid; b < NBKT; b += 4) { // coalesced flush
        int n = bincnt[b], bb = binbase[b];
        for (int i = lane; i < n; i += 64)
            staging[bb + i] = bins[b][i];
    }
}

// ---- Pass 2: exact placement via LDS cursors. csr.x stores the BYTE row
// offset (col*256) so the spmm gather address is one v_add.
__global__ __launch_bounds__(256) void k_scat2(const int* __restrict__ row_ptr,
                                               const int2* __restrict__ staging,
                                               int2* __restrict__ csr) {
    __shared__ int cur[BKT_W];
    const int nb = blockIdx.x << BKT_SH;
    for (int t = threadIdx.x; t < BKT_W; t += 256) {
        int node = nb + t;
        cur[t] = (node < NN) ? row_ptr[node] : 0;
    }
    __syncthreads();
    const int beg = row_ptr[nb];
    const int end = row_ptr[min(nb + BKT_W, NN)];
    for (int i = beg + threadIdx.x; i < end; i += 256) {
        int2 cv = staging[i];
        int dl = cv.x >> 17;
        int p  = atomicAdd(&cur[dl], 1);
        csr[p] = make_int2((cv.x & 0x1FFFF) << 8, cv.y);   // byte offset of row
    }
}

// ---- shared gather core: 2 rows, masked-uniform 8+8 deep, no drains -------
// All edge data rides the scalar pipe (uniform csr indices); OOB slots clamp
// the index (L1-hit duplicate) and zero the value (s_cselect).
__device__ __forceinline__ void spmm2rows(const float* __restrict__ in,
                                          const int* __restrict__ row_ptr,
                                          const int2* __restrict__ csr,
                                          int ra, int lane,
                                          float& outA, float& outB) {
    const char* inB = (const char*)in + (lane << 2);
    const int begA = row_ptr[ra],     endA = row_ptr[ra + 1];
    const int begB = row_ptr[ra + 1], endB = row_ptr[ra + 2];
    const int lastA = (endA > begA) ? endA - 1 : begA;   // safe clamp target
    const int lastB = (endB > begB) ? endB - 1 : begB;
    const int lenA = endA - begA, lenB = endB - begB;
    const int trips = (max(lenA, lenB) + 7) >> 3;

    float a0 = 0.f, a1 = 0.f, a2 = 0.f, a3 = 0.f;
    float b0 = 0.f, b1 = 0.f, b2 = 0.f, b3 = 0.f;
    int ja = begA, jb = begB;
    for (int t = 0; t < trips; ++t) {
        int2 eA[8], eB[8];
        #pragma unroll
        for (int u = 0; u < 8; ++u) {
            eA[u] = csr[min(ja + u, lastA)];
            eB[u] = csr[min(jb + u, lastB)];
        }
        #pragma unroll
        for (int u = 0; u < 8; ++u) {
            if (ja + u >= endA) eA[u].y = 0;
            if (jb + u >= endB) eB[u].y = 0;
        }
        float gA[8], gB[8];
        #pragma unroll
        for (int u = 0; u < 8; ++u) {
            gA[u] = *(const float*)(inB + eA[u].x);
            gB[u] = *(const float*)(inB + eB[u].x);
        }
        a0 += __int_as_float(eA[0].y) * gA[0]; a1 += __int_as_float(eA[1].y) * gA[1];
        a2 += __int_as_float(eA[2].y) * gA[2]; a3 += __int_as_float(eA[3].y) * gA[3];
        a0 += __int_as_float(eA[4].y) * gA[4]; a1 += __int_as_float(eA[5].y) * gA[5];
        a2 += __int_as_float(eA[6].y) * gA[6]; a3 += __int_as_float(eA[7].y) * gA[7];
        b0 += __int_as_float(eB[0].y) * gB[0]; b1 += __int_as_float(eB[1].y) * gB[1];
        b2 += __int_as_float(eB[2].y) * gB[2]; b3 += __int_as_float(eB[3].y) * gB[3];
        b0 += __int_as_float(eB[4].y) * gB[4]; b1 += __int_as_float(eB[5].y) * gB[5];
        b2 += __int_as_float(eB[6].y) * gB[6]; b3 += __int_as_float(eB[7].y) * gB[7];
        ja += 8; jb += 8;
    }
    outA = (a0 + a1) + (a2 + a3);
    outB = (b0 + b1) + (b2 + b3);
}

// ---------------- SPMM1: h = relu(spmm(xw) + b1) ----------------------------
__global__ __launch_bounds__(512) void k_spmm1(const float* __restrict__ in,
                                               const int* __restrict__ row_ptr,
                                               const int2* __restrict__ csr,
                                               const float* __restrict__ bias,
                                               float* __restrict__ out) {
    const int lane = threadIdx.x & 63;
    const int gw   = (blockIdx.x * 512 + threadIdx.x) >> 6;
    const int ra   = __builtin_amdgcn_readfirstlane(gw * 2);   // grid exact
    float sA, sB;
    spmm2rows(in, row_ptr, csr, ra, lane, sA, sB);
    float fb = bias[lane];
    out[(size_t)ra * NHID + lane]       = fmaxf(sA + fb, 0.f);
    out[(size_t)(ra + 1) * NHID + lane] = fmaxf(sB + fb, 0.f);
}

// ---------------- Fused SPMM2 + heads + reparam + log_softmax ---------------
// 512-thread blocks: 16 rows/block, W-LDS amortized, no LDS occupancy cap.
__global__ __launch_bounds__(512) void k_spmm_final(const float* __restrict__ h,
                                                    const int* __restrict__ row_ptr,
                                                    const int2* __restrict__ csr,
                                                    const float* __restrict__ W11,
                                                    const float* __restrict__ b11,
                                                    const float* __restrict__ W12,
                                                    const float* __restrict__ b12,
                                                    const float* __restrict__ eps,
                                                    float* __restrict__ out) {
    __shared__ float W11l[NHID * NCLASS];   // 10 KB
    __shared__ float W12l[NHID * NCLASS];   // 10 KB
    __shared__ float bl[2 * NCLASS];
    __shared__ float grow[16][NHID];        // 16 rows per block, 4 KB
    for (int i = threadIdx.x; i < NHID * NCLASS; i += 512) {
        W11l[i] = W11[i];
        W12l[i] = W12[i];
    }
    if (threadIdx.x < NCLASS) bl[threadIdx.x] = b11[threadIdx.x];
    else if (threadIdx.x < 2 * NCLASS) bl[threadIdx.x] = b12[threadIdx.x - NCLASS];

    const int lane = threadIdx.x & 63;
    const int wv   = threadIdx.x >> 6;                          // 0..7
    const int ra   = __builtin_amdgcn_readfirstlane((blockIdx.x * 8 + wv) * 2);
    const int rb   = ra + 1;

    float sA, sB;
    spmm2rows(h, row_ptr, csr, ra, lane, sA, sB);
    grow[wv * 2 + 0][lane] = sA;
    grow[wv * 2 + 1][lane] = sB;
    __syncthreads();   // also covers the W/b LDS loads above

    // ---- heads for both rows; lane cc < NCLASS owns a class ----
    const bool act = lane < NCLASS;
    const int  cc  = act ? lane : NCLASS - 1;
    float m0 = bl[cc],          m1 = m0;
    float l0 = bl[NCLASS + cc], l1 = l0;
    #pragma unroll 8
    for (int k = 0; k < NHID; ++k) {
        float w1 = W11l[k * NCLASS + cc];
        float w2 = W12l[k * NCLASS + cc];
        float g0 = grow[wv * 2 + 0][k];     // LDS broadcast
        float g1 = grow[wv * 2 + 1][k];
        m0 += g0 * w1; l0 += g0 * w2;
        m1 += g1 * w1; l1 += g1 * w2;
    }

    float z0 = act ? (eps[(size_t)ra * NCLASS + lane] * expf(l0) + m0) : -1e30f;
    float z1 = act ? (eps[(size_t)rb * NCLASS + lane] * expf(l1) + m1) : -1e30f;

    float zm0 = z0, zm1 = z1;
    #pragma unroll
    for (int off = 32; off >= 1; off >>= 1) {
        zm0 = fmaxf(zm0, __shfl_xor(zm0, off));
        zm1 = fmaxf(zm1, __shfl_xor(zm1, off));
    }
    float s0 = act ? expf(z0 - zm0) : 0.f;
    float s1 = act ? expf(z1 - zm1) : 0.f;
    #pragma unroll
    for (int off = 32; off >= 1; off >>= 1) {
        s0 += __shfl_xor(s0, off);
        s1 += __shfl_xor(s1, off);
    }
    if (act) {
        out[(size_t)ra * NCLASS + lane] = z0 - zm0 - logf(s0);
        out[(size_t)rb * NCLASS + lane] = z1 - zm1 - logf(s1);
    }
}

// ---------------- launcher --------------------------------------------------
extern "C" void kernel_launch(void* const* d_in, const int* in_sizes, int n_in,
                              void* d_out, int out_size, void* d_ws, size_t ws_size,
                              hipStream_t stream) {
    const float* x        = (const float*)d_in[0];
    const int*   edge_src = (const int*)d_in[1];
    const int*   edge_dst = (const int*)d_in[2];
    const float* edge_val = (const float*)d_in[3];
    const float* eps      = (const float*)d_in[4];
    const float* W1       = (const float*)d_in[5];
    const float* b1       = (const float*)d_in[6];
    const float* W11      = (const float*)d_in[7];
    const float* b11      = (const float*)d_in[8];
    const float* W12      = (const float*)d_in[9];
    const float* b12      = (const float*)d_in[10];
    float* out = (float*)d_out;

    // ws layout; staging aliases h (h first written in spmm1, after scat2)
    int2*  csr     = (int2*)d_ws;                  // EDGES * 8B
    float* xw      = (float*)(csr + EDGES);        // NN*64
    float* h       = xw + (size_t)NN * NHID;       // NN*64
    int2*  staging = (int2*)h;                     // EDGES * 8B (alias)
    int*   count   = (int*)(h + (size_t)NN * NHID);
    int*   tmp     = count + NN;
    int*   row_ptr = tmp + NN;                     // NN+1
    int*   bcur    = row_ptr + (NN + 1);           // NBKT
    int*   blocksum= bcur + NBKT;
    int*   blockoff= blocksum + 128;

    const int NB = (NN + SCAN_BLK - 1) / SCAN_BLK; // 98

    k_gemm1<<<(NN + BM - 1) / BM, 256, 0, stream>>>(x, W1, xw);
    k_zero<<<(NN + 255) / 256, 256, 0, stream>>>(count);
    k_hist<<<(EDGES / 4 + 255) / 256, 256, 0, stream>>>(edge_dst, count);
    k_scanA<<<NB, SCAN_BLK, 0, stream>>>(count, tmp, blocksum);
    k_scanB<<<1, 128, 0, stream>>>(blocksum, blockoff, NB);
    k_scanC<<<(NN + 255) / 256, 256, 0, stream>>>(tmp, blockoff, count, row_ptr, bcur);
    k_scat1<<<NBLK1, 256, 0, stream>>>(edge_src, edge_dst, edge_val, bcur, staging);
    k_scat2<<<NBKT, 256, 0, stream>>>(row_ptr, staging, csr);
    k_spmm1<<<NN / 16, 512, 0, stream>>>(xw, row_ptr, csr, b1, h);
    k_spmm_final<<<NN / 16, 512, 0, stream>>>(h, row_ptr, csr, W11, b11, W12, b12,
                                              eps, out);
}